// Round 2
// baseline (6652.631 us; speedup 1.0000x reference)
//
#include <hip/hip_runtime.h>
#include <stdint.h>
#include <math.h>

#define D_CAT  1024
#define R_TR   64
#define RR     4096      // R*R
#define NDRAWS 2048
#define KMODES 8

struct CorePtrs { const float* p[KMODES]; };

// ---------------- threefry2x32 (JAX-exact, 20 rounds) ----------------
static __host__ __device__ inline uint32_t rotl32(uint32_t x, int r) {
  return (x << r) | (x >> (32 - r));
}
static __host__ __device__ inline void tf2x32(uint32_t k1, uint32_t k2,
                                              uint32_t x0, uint32_t x1,
                                              uint32_t& o0, uint32_t& o1) {
  uint32_t ks0 = k1, ks1 = k2, ks2 = k1 ^ k2 ^ 0x1BD11BDAu;
  x0 += ks0; x1 += ks1;
  x0 += x1; x1 = rotl32(x1, 13); x1 ^= x0;
  x0 += x1; x1 = rotl32(x1, 15); x1 ^= x0;
  x0 += x1; x1 = rotl32(x1, 26); x1 ^= x0;
  x0 += x1; x1 = rotl32(x1, 6);  x1 ^= x0;
  x0 += ks1; x1 += ks2 + 1u;
  x0 += x1; x1 = rotl32(x1, 17); x1 ^= x0;
  x0 += x1; x1 = rotl32(x1, 29); x1 ^= x0;
  x0 += x1; x1 = rotl32(x1, 16); x1 ^= x0;
  x0 += x1; x1 = rotl32(x1, 24); x1 ^= x0;
  x0 += ks2; x1 += ks0 + 2u;
  x0 += x1; x1 = rotl32(x1, 13); x1 ^= x0;
  x0 += x1; x1 = rotl32(x1, 15); x1 ^= x0;
  x0 += x1; x1 = rotl32(x1, 26); x1 ^= x0;
  x0 += x1; x1 = rotl32(x1, 6);  x1 ^= x0;
  x0 += ks0; x1 += ks1 + 3u;
  x0 += x1; x1 = rotl32(x1, 17); x1 ^= x0;
  x0 += x1; x1 = rotl32(x1, 29); x1 ^= x0;
  x0 += x1; x1 = rotl32(x1, 16); x1 ^= x0;
  x0 += x1; x1 = rotl32(x1, 24); x1 ^= x0;
  x0 += ks1; x1 += ks2 + 4u;
  x0 += x1; x1 = rotl32(x1, 13); x1 ^= x0;
  x0 += x1; x1 = rotl32(x1, 15); x1 ^= x0;
  x0 += x1; x1 = rotl32(x1, 26); x1 ^= x0;
  x0 += x1; x1 = rotl32(x1, 6);  x1 ^= x0;
  x0 += ks2; x1 += ks0 + 5u;
  o0 = x0; o1 = x1;
}

// softplus exactly as jnp.logaddexp(x, 0): max(x,0) + log1p(exp(-|x|))
static __device__ inline float softplus_ref(float x) {
  return fmaxf(x, 0.0f) + log1pf(expf(-fabsf(x)));
}

// gumbel for flat element e under key (k1,k2), partitionable path:
// counter=(0,e), bits = o1^o2
static __device__ inline float gumbel_at(uint32_t k1, uint32_t k2, uint32_t e) {
  uint32_t o0, o1;
  tf2x32(k1, k2, 0u, e, o0, o1);
  uint32_t bits = o0 ^ o1;
  float f = __uint_as_float((bits >> 9) | 0x3F800000u) - 1.0f;
  float u = (f > 0.0f) ? f : 1.17549435e-38f;   // finfo(f32).tiny
  return -logf(-logf(u));
}

// ---------------- kernels ----------------

__global__ void k_sentinel(float* out, int n) {
  int i = blockIdx.x * 256 + threadIdx.x;
  if (i < n) out[i] = -12288.0f;  // ws-too-small marker
}

// partial column sums of softplus(core_i): grid 8*64, block 256
__global__ __launch_bounds__(256) void k_spart(CorePtrs cp, double* __restrict__ Spart) {
  const int bid = blockIdx.x, tid = threadIdx.x;
  const int i = bid >> 6, c = bid & 63;           // core i, d-chunk c (16 d's)
  const float* src = cp.p[i];
  double acc[16];
#pragma unroll
  for (int k = 0; k < 16; ++k) acc[k] = 0.0;
  for (int d = c * 16; d < c * 16 + 16; ++d) {
    const float* row = src + (size_t)d * RR;
#pragma unroll
    for (int k = 0; k < 16; ++k)
      acc[k] += (double)softplus_ref(row[tid + k * 256]);
  }
  double* dst = Spart + (size_t)(i * 64 + c) * RR;
#pragma unroll
  for (int k = 0; k < 16; ++k) dst[tid + k * 256] = acc[k];
}

// reduce 64 partials -> S[i][rr]: grid 128, block 256
__global__ __launch_bounds__(256) void k_sreduce(const double* __restrict__ Spart,
                                                 double* __restrict__ S) {
  const int idx = blockIdx.x * 256 + threadIdx.x;   // 0..32767
  const int i = idx >> 12, rr = idx & 4095;
  double acc = 0.0;
  for (int c = 0; c < 64; ++c)
    acc += Spart[(size_t)(i * 64 + c) * RR + rr];
  S[(size_t)i * RR + rr] = acc;
}

// heads chain + log(trace(norm)): 1 block, 256 threads
__global__ __launch_bounds__(256) void k_heads(const double* __restrict__ S,
                                               double* __restrict__ heads,
                                               double* __restrict__ misc) {
  __shared__ double bufA[RR];
  __shared__ double bufB[RR];
  const int tid = threadIdx.x;
  double* cur = bufA; double* nxt = bufB;
  for (int k = 0; k < 16; ++k) {
    int p = tid + k * 256;
    double v = S[p];               // S0
    cur[p] = v;
    heads[p] = v;                  // slot 0 = heads[1] = S0
  }
  __syncthreads();
  for (int m = 1; m <= 6; ++m) {
    for (int k = 0; k < 16; ++k) {
      int p = tid + k * 256; int a = p >> 6, bcol = p & 63;
      double acc = 0.0;
      for (int c = 0; c < 64; ++c)
        acc = fma(cur[a * 64 + c], S[(size_t)m * RR + c * 64 + bcol], acc);
      nxt[p] = acc;
    }
    __syncthreads();
    for (int k = 0; k < 16; ++k) {
      int p = tid + k * 256;
      heads[(size_t)m * RR + p] = nxt[p];   // slot m = heads[m+1]
    }
    double* t = cur; cur = nxt; nxt = t;
    __syncthreads();
  }
  // trace(norm) = trace(heads[7] @ S7)
  if (tid < 64) {
    double acc = 0.0;
    for (int c = 0; c < 64; ++c)
      acc = fma(cur[tid * 64 + c], S[(size_t)7 * RR + c * 64 + tid], acc);
    nxt[tid] = acc;
  }
  __syncthreads();
  if (tid == 0) {
    double tr = 0.0;
    for (int a = 0; a < 64; ++a) tr += nxt[a];
    misc[0] = log(tr);
  }
}

// softplus(log_core_j) -> Core: grid 4096, block 256, 4 elems/thread
__global__ __launch_bounds__(256) void k_softplus(const float* __restrict__ src,
                                                  float* __restrict__ dst) {
  const size_t i4 = ((size_t)blockIdx.x * 256 + threadIdx.x) * 4;
  float4 v = *(const float4*)(src + i4);
  float4 o;
  o.x = softplus_ref(v.x); o.y = softplus_ref(v.y);
  o.z = softplus_ref(v.z); o.w = softplus_ref(v.w);
  *(float4*)(dst + i4) = o;
}

// step 0 weights: w[n] = sum_q Core[n,q] * heads7[(q&63)*64 + (q>>6)]
__global__ __launch_bounds__(256) void k_w0(const float* __restrict__ Core,
                                            const double* __restrict__ head7,
                                            float* __restrict__ W) {
  const int tid = threadIdx.x;
  const int lane = tid & 63;
  const int n = blockIdx.x * 4 + (tid >> 6);
  const float* crow = Core + (size_t)n * RR;
  double acc = 0.0;
  for (int q = lane; q < RR; q += 64)
    acc = fma((double)crow[q], head7[(q & 63) * 64 + (q >> 6)], acc);
  for (int m = 32; m; m >>= 1) acc += __shfl_xor(acc, m);
  if (lane == 0) W[n] = (float)acc;
}

// Mt[b, a*64+bb] = sum_c tail[b,bb,c]*head[c,a]   (or transpose if !useHead)
__global__ __launch_bounds__(256) void k_mt(const float* __restrict__ tail,
                                            const double* __restrict__ head,
                                            float* __restrict__ Mt, int useHead) {
  __shared__ float tl[64 * 65];
  const int b = blockIdx.x, tid = threadIdx.x;
  const float* trow = tail + (size_t)b * RR;
  for (int k = 0; k < 16; ++k) {
    int q = tid + k * 256;
    tl[(q >> 6) * 65 + (q & 63)] = trow[q];
  }
  __syncthreads();
  float* mrow = Mt + (size_t)b * RR;
  for (int k = 0; k < 16; ++k) {
    int p = tid + k * 256; int a = p >> 6, bb = p & 63;
    if (useHead) {
      double acc = 0.0;
      for (int c = 0; c < 64; ++c)
        acc = fma((double)tl[bb * 65 + c], head[c * 64 + a], acc);
      mrow[p] = (float)acc;
    } else {
      mrow[p] = tl[bb * 65 + a];
    }
  }
}

// W[2048x1024] = Mt[2048x4096] * Core^T, f64 accumulate.
__global__ __launch_bounds__(256) void k_wgemm(const float* __restrict__ A,
                                               const float* __restrict__ B,
                                               float* __restrict__ W) {
  __shared__ float As[64][36];
  __shared__ float Bs[64][36];
  const int tid = threadIdx.x;
  const int tx = tid & 15, ty = tid >> 4;
  const int bn = blockIdx.x, bb = blockIdx.y;
  const float* Ag = A + (size_t)bb * 64 * RR;
  const float* Bg = B + (size_t)bn * 64 * RR;
  double acc[4][4];
#pragma unroll
  for (int i = 0; i < 4; ++i)
#pragma unroll
    for (int j = 0; j < 4; ++j) acc[i][j] = 0.0;
  const int lr = tid >> 2;          // 0..63
  const int lc = (tid & 3) * 8;     // 0,8,16,24
  for (int k0 = 0; k0 < RR; k0 += 32) {
    __syncthreads();
    float4 a0 = *(const float4*)(Ag + (size_t)lr * RR + k0 + lc);
    float4 a1 = *(const float4*)(Ag + (size_t)lr * RR + k0 + lc + 4);
    float4 b0 = *(const float4*)(Bg + (size_t)lr * RR + k0 + lc);
    float4 b1 = *(const float4*)(Bg + (size_t)lr * RR + k0 + lc + 4);
    *(float4*)(&As[lr][lc])     = a0;
    *(float4*)(&As[lr][lc + 4]) = a1;
    *(float4*)(&Bs[lr][lc])     = b0;
    *(float4*)(&Bs[lr][lc + 4]) = b1;
    __syncthreads();
#pragma unroll 8
    for (int kk = 0; kk < 32; ++kk) {
      double a[4], b[4];
#pragma unroll
      for (int i = 0; i < 4; ++i) a[i] = (double)As[ty * 4 + i][kk];
#pragma unroll
      for (int j = 0; j < 4; ++j) b[j] = (double)Bs[tx * 4 + j][kk];
#pragma unroll
      for (int i = 0; i < 4; ++i)
#pragma unroll
        for (int j = 0; j < 4; ++j)
          acc[i][j] = fma(a[i], b[j], acc[i][j]);
    }
  }
  for (int i = 0; i < 4; ++i) {
    int gr = bb * 64 + ty * 4 + i;
    for (int j = 0; j < 4; ++j) {
      int gc = bn * 64 + tx * 4 + j;
      W[(size_t)gr * D_CAT + gc] = (float)acc[i][j];
    }
  }
}

// per-draw gumbel-argmax over 1024 categories
__global__ __launch_bounds__(256) void k_sample(const float* __restrict__ W, int shared_row,
                                                uint32_t key1, uint32_t key2,
                                                int* __restrict__ ixout,
                                                float* __restrict__ out, int mode_j) {
  const int b = blockIdx.x, tid = threadIdx.x;
  const float* wrow = W + (shared_row ? 0 : (size_t)b * D_CAT);
  float best = -3.4e38f; int bidx = 0x7fffffff;
  for (int k = 0; k < 4; ++k) {
    int n = tid + k * 256;
    float lg = logf(fmaxf(wrow[n], 1e-30f));
    float v = gumbel_at(key1, key2, (uint32_t)(b * D_CAT + n)) + lg;
    if (v > best || (v == best && n < bidx)) { best = v; bidx = n; }
  }
  for (int m = 32; m; m >>= 1) {
    float ov = __shfl_xor(best, m);
    int   oi = __shfl_xor(bidx, m);
    if (ov > best || (ov == best && oi < bidx)) { best = ov; bidx = oi; }
  }
  __shared__ float sv[4];
  __shared__ int   si[4];
  if ((tid & 63) == 0) { sv[tid >> 6] = best; si[tid >> 6] = bidx; }
  __syncthreads();
  if (tid == 0) {
    for (int t = 1; t < 4; ++t)
      if (sv[t] > best || (sv[t] == best && si[t] < bidx)) { best = sv[t]; bidx = si[t]; }
    ixout[b] = bidx;
    out[b * KMODES + mode_j] = (float)bidx;
  }
}

// tail[b] = Core[ix_b] (first) or Core[ix_b] @ tail[b] (in place)
__global__ __launch_bounds__(256) void k_tail(const float* __restrict__ Core,
                                              const int* __restrict__ ix,
                                              float* __restrict__ tail, int first) {
  const int b = blockIdx.x, tid = threadIdx.x;
  const int m = ix[b];
  const float* crow = Core + (size_t)m * RR;
  float* trow = tail + (size_t)b * RR;
  if (first) {
    for (int k = 0; k < 16; ++k) trow[tid + k * 256] = crow[tid + k * 256];
    return;
  }
  __shared__ float tl[RR];
  for (int k = 0; k < 16; ++k) tl[tid + k * 256] = trow[tid + k * 256];
  __syncthreads();
  float outv[16];
  for (int k = 0; k < 16; ++k) {
    int p = tid + k * 256; int a = p >> 6, bb = p & 63;
    double acc = 0.0;
    for (int c = 0; c < 64; ++c)
      acc = fma((double)crow[a * 64 + c], (double)tl[c * 64 + bb], acc);
    outv[k] = (float)acc;
  }
  for (int k = 0; k < 16; ++k) trow[tid + k * 256] = outv[k];
}

__global__ __launch_bounds__(256) void k_logp(const float* __restrict__ tail,
                                              const double* __restrict__ misc,
                                              float* __restrict__ out) {
  const int b = blockIdx.x * 256 + threadIdx.x;   // 0..2047
  double tr = 0.0;
  for (int a = 0; a < 64; ++a) tr += (double)tail[(size_t)b * RR + a * 65];
  double lp = log(fmax(tr, 1e-30)) - misc[0];
  out[NDRAWS * KMODES + b] = (float)lp;
}

// ---------------- launcher ----------------
extern "C" void kernel_launch(void* const* d_in, const int* in_sizes, int n_in,
                              void* d_out, int out_size, void* d_ws, size_t ws_size,
                              hipStream_t stream) {
  (void)in_sizes; (void)n_in;
  CorePtrs cp;
  for (int i = 0; i < KMODES; ++i) cp.p[i] = (const float*)d_in[i];
  float* outf = (float*)d_out;

  char* base = (char*)d_ws;
  const size_t o_core  = 0;                                    // f32 1024*4096
  const size_t o_w     = o_core + (size_t)D_CAT * RR * 4;      // f32 2048*1024
  const size_t o_tail  = o_w + (size_t)NDRAWS * D_CAT * 4;     // f32 2048*4096
  const size_t o_mt    = o_tail + (size_t)NDRAWS * RR * 4;     // f32 2048*4096
  const size_t o_spart = o_mt;                                 // overlap (16MB < 33.5MB)
  const size_t o_S     = o_mt + (size_t)NDRAWS * RR * 4;       // f64 8*4096
  const size_t o_heads = o_S + (size_t)KMODES * RR * 8;        // f64 7*4096
  const size_t o_ix    = o_heads + (size_t)7 * RR * 8;         // i32 2048
  const size_t o_misc  = o_ix + (size_t)NDRAWS * 4;            // f64 lognorm
  const size_t NEED    = o_misc + 256;
  if (ws_size < NEED) {
    k_sentinel<<<(out_size + 255) / 256, 256, 0, stream>>>(outf, out_size);
    return;
  }

  float*  Core  = (float*)(base + o_core);
  float*  W     = (float*)(base + o_w);
  float*  tail  = (float*)(base + o_tail);
  float*  Mt    = (float*)(base + o_mt);
  double* Spart = (double*)(base + o_spart);
  double* S     = (double*)(base + o_S);
  double* heads = (double*)(base + o_heads);
  int*    ix    = (int*)(base + o_ix);
  double* misc  = (double*)(base + o_misc);

  // keys[s] = threefry2x32((0,1), (0,s))  -- split(key(1), 8), foldlike
  uint32_t kk1[KMODES], kk2[KMODES];
  for (uint32_t s = 0; s < KMODES; ++s) tf2x32(0u, 1u, 0u, s, kk1[s], kk2[s]);

  k_spart  <<<512, 256, 0, stream>>>(cp, Spart);
  k_sreduce<<<128, 256, 0, stream>>>(Spart, S);
  k_heads  <<<1,   256, 0, stream>>>(S, heads, misc);

  for (int s = 0; s < KMODES; ++s) {
    const int j = 7 - s;
    k_softplus<<<4096, 256, 0, stream>>>(cp.p[j], Core);
    if (s == 0) {
      k_w0<<<256, 256, 0, stream>>>(Core, heads + (size_t)6 * RR, W);
    } else {
      k_mt<<<2048, 256, 0, stream>>>(tail, j > 0 ? heads + (size_t)(j - 1) * RR : nullptr,
                                     Mt, j > 0 ? 1 : 0);
      k_wgemm<<<dim3(16, 32), 256, 0, stream>>>(Mt, Core, W);
    }
    k_sample<<<NDRAWS, 256, 0, stream>>>(W, s == 0 ? 1 : 0, kk1[s], kk2[s], ix, outf, j);
    k_tail  <<<NDRAWS, 256, 0, stream>>>(Core, ix, tail, s == 0 ? 1 : 0);
  }
  k_logp<<<KMODES, 256, 0, stream>>>(tail, misc, outf);
}

// Round 3
// 4851.816 us; speedup vs baseline: 1.3712x; 1.3712x over previous
//
#include <hip/hip_runtime.h>
#include <stdint.h>
#include <math.h>

#define D_CAT  1024
#define R_TR   64
#define RR     4096      // R*R
#define NDRAWS 2048
#define KMODES 8

struct CorePtrs { const float* p[KMODES]; };

// ---------------- threefry2x32 (JAX-exact, 20 rounds) ----------------
static __host__ __device__ inline uint32_t rotl32(uint32_t x, int r) {
  return (x << r) | (x >> (32 - r));
}
static __host__ __device__ inline void tf2x32(uint32_t k1, uint32_t k2,
                                              uint32_t x0, uint32_t x1,
                                              uint32_t& o0, uint32_t& o1) {
  uint32_t ks0 = k1, ks1 = k2, ks2 = k1 ^ k2 ^ 0x1BD11BDAu;
  x0 += ks0; x1 += ks1;
  x0 += x1; x1 = rotl32(x1, 13); x1 ^= x0;
  x0 += x1; x1 = rotl32(x1, 15); x1 ^= x0;
  x0 += x1; x1 = rotl32(x1, 26); x1 ^= x0;
  x0 += x1; x1 = rotl32(x1, 6);  x1 ^= x0;
  x0 += ks1; x1 += ks2 + 1u;
  x0 += x1; x1 = rotl32(x1, 17); x1 ^= x0;
  x0 += x1; x1 = rotl32(x1, 29); x1 ^= x0;
  x0 += x1; x1 = rotl32(x1, 16); x1 ^= x0;
  x0 += x1; x1 = rotl32(x1, 24); x1 ^= x0;
  x0 += ks2; x1 += ks0 + 2u;
  x0 += x1; x1 = rotl32(x1, 13); x1 ^= x0;
  x0 += x1; x1 = rotl32(x1, 15); x1 ^= x0;
  x0 += x1; x1 = rotl32(x1, 26); x1 ^= x0;
  x0 += x1; x1 = rotl32(x1, 6);  x1 ^= x0;
  x0 += ks0; x1 += ks1 + 3u;
  x0 += x1; x1 = rotl32(x1, 17); x1 ^= x0;
  x0 += x1; x1 = rotl32(x1, 29); x1 ^= x0;
  x0 += x1; x1 = rotl32(x1, 16); x1 ^= x0;
  x0 += x1; x1 = rotl32(x1, 24); x1 ^= x0;
  x0 += ks1; x1 += ks2 + 4u;
  x0 += x1; x1 = rotl32(x1, 13); x1 ^= x0;
  x0 += x1; x1 = rotl32(x1, 15); x1 ^= x0;
  x0 += x1; x1 = rotl32(x1, 26); x1 ^= x0;
  x0 += x1; x1 = rotl32(x1, 6);  x1 ^= x0;
  x0 += ks2; x1 += ks0 + 5u;
  o0 = x0; o1 = x1;
}

// softplus exactly as jnp.logaddexp(x, 0): max(x,0) + log1p(exp(-|x|))
static __device__ inline float softplus_ref(float x) {
  return fmaxf(x, 0.0f) + log1pf(expf(-fabsf(x)));
}

// gumbel for flat element e under key (k1,k2), partitionable path:
// counter=(0,e), bits = o1^o2
static __device__ inline float gumbel_at(uint32_t k1, uint32_t k2, uint32_t e) {
  uint32_t o0, o1;
  tf2x32(k1, k2, 0u, e, o0, o1);
  uint32_t bits = o0 ^ o1;
  float f = __uint_as_float((bits >> 9) | 0x3F800000u) - 1.0f;
  float u = (f > 0.0f) ? f : 1.17549435e-38f;   // finfo(f32).tiny
  return -logf(-logf(u));
}

// ---------------- kernels ----------------

__global__ void k_sentinel(float* out, int n) {
  int i = blockIdx.x * 256 + threadIdx.x;
  if (i < n) out[i] = -12288.0f;  // ws-too-small marker
}

// partial column sums of softplus(core_i): grid 8*64, block 256
__global__ __launch_bounds__(256) void k_spart(CorePtrs cp, double* __restrict__ Spart) {
  const int bid = blockIdx.x, tid = threadIdx.x;
  const int i = bid >> 6, c = bid & 63;           // core i, d-chunk c (16 d's)
  const float* src = cp.p[i];
  double acc[16];
#pragma unroll
  for (int k = 0; k < 16; ++k) acc[k] = 0.0;
  for (int d = c * 16; d < c * 16 + 16; ++d) {
    const float* row = src + (size_t)d * RR;
#pragma unroll
    for (int k = 0; k < 16; ++k)
      acc[k] += (double)softplus_ref(row[tid + k * 256]);
  }
  double* dst = Spart + (size_t)(i * 64 + c) * RR;
#pragma unroll
  for (int k = 0; k < 16; ++k) dst[tid + k * 256] = acc[k];
}

// reduce 64 partials -> S[i][rr]: grid 128, block 256
__global__ __launch_bounds__(256) void k_sreduce(const double* __restrict__ Spart,
                                                 double* __restrict__ S) {
  const int idx = blockIdx.x * 256 + threadIdx.x;   // 0..32767
  const int i = idx >> 12, rr = idx & 4095;
  double acc = 0.0;
  for (int c = 0; c < 64; ++c)
    acc += Spart[(size_t)(i * 64 + c) * RR + rr];
  S[(size_t)i * RR + rr] = acc;
}

// heads chain + log(trace(norm)): 1 block, 256 threads
__global__ __launch_bounds__(256) void k_heads(const double* __restrict__ S,
                                               double* __restrict__ heads,
                                               double* __restrict__ misc) {
  __shared__ double bufA[RR];
  __shared__ double bufB[RR];
  const int tid = threadIdx.x;
  double* cur = bufA; double* nxt = bufB;
  for (int k = 0; k < 16; ++k) {
    int p = tid + k * 256;
    double v = S[p];               // S0
    cur[p] = v;
    heads[p] = v;                  // slot 0 = heads[1] = S0
  }
  __syncthreads();
  for (int m = 1; m <= 6; ++m) {
    for (int k = 0; k < 16; ++k) {
      int p = tid + k * 256; int a = p >> 6, bcol = p & 63;
      double acc = 0.0;
      for (int c = 0; c < 64; ++c)
        acc = fma(cur[a * 64 + c], S[(size_t)m * RR + c * 64 + bcol], acc);
      nxt[p] = acc;
    }
    __syncthreads();
    for (int k = 0; k < 16; ++k) {
      int p = tid + k * 256;
      heads[(size_t)m * RR + p] = nxt[p];   // slot m = heads[m+1]
    }
    double* t = cur; cur = nxt; nxt = t;
    __syncthreads();
  }
  // trace(norm) = trace(heads[7] @ S7)
  if (tid < 64) {
    double acc = 0.0;
    for (int c = 0; c < 64; ++c)
      acc = fma(cur[tid * 64 + c], S[(size_t)7 * RR + c * 64 + tid], acc);
    nxt[tid] = acc;
  }
  __syncthreads();
  if (tid == 0) {
    double tr = 0.0;
    for (int a = 0; a < 64; ++a) tr += nxt[a];
    misc[0] = log(tr);
  }
}

// softplus(log_core_j) -> Core: grid 4096, block 256, 4 elems/thread
__global__ __launch_bounds__(256) void k_softplus(const float* __restrict__ src,
                                                  float* __restrict__ dst) {
  const size_t i4 = ((size_t)blockIdx.x * 256 + threadIdx.x) * 4;
  float4 v = *(const float4*)(src + i4);
  float4 o;
  o.x = softplus_ref(v.x); o.y = softplus_ref(v.y);
  o.z = softplus_ref(v.z); o.w = softplus_ref(v.w);
  *(float4*)(dst + i4) = o;
}

// step 0 weights: w[n] = sum_q Core[n,q] * heads7[(q&63)*64 + (q>>6)]
__global__ __launch_bounds__(256) void k_w0(const float* __restrict__ Core,
                                            const double* __restrict__ head7,
                                            float* __restrict__ W) {
  const int tid = threadIdx.x;
  const int lane = tid & 63;
  const int n = blockIdx.x * 4 + (tid >> 6);
  const float* crow = Core + (size_t)n * RR;
  double acc = 0.0;
  for (int q = lane; q < RR; q += 64)
    acc = fma((double)crow[q], head7[(q & 63) * 64 + (q >> 6)], acc);
  for (int m = 32; m; m >>= 1) acc += __shfl_xor(acc, m);
  if (lane == 0) W[n] = (float)acc;
}

// Mt[b, a*64+bb] = sum_c tail[b,bb,c]*head[c,a]   (or transpose if !useHead)
__global__ __launch_bounds__(256) void k_mt(const float* __restrict__ tail,
                                            const double* __restrict__ head,
                                            float* __restrict__ Mt, int useHead) {
  __shared__ float tl[64 * 65];
  const int b = blockIdx.x, tid = threadIdx.x;
  const float* trow = tail + (size_t)b * RR;
  for (int k = 0; k < 16; ++k) {
    int q = tid + k * 256;
    tl[(q >> 6) * 65 + (q & 63)] = trow[q];
  }
  __syncthreads();
  float* mrow = Mt + (size_t)b * RR;
  for (int k = 0; k < 16; ++k) {
    int p = tid + k * 256; int a = p >> 6, bb = p & 63;
    if (useHead) {
      double acc = 0.0;
      for (int c = 0; c < 64; ++c)
        acc = fma((double)tl[bb * 65 + c], head[c * 64 + a], acc);
      mrow[p] = (float)acc;
    } else {
      mrow[p] = tl[bb * 65 + a];
    }
  }
}

// W[2048x1024] = Mt[2048x4096] * Core^T.
// f32 products, chunk-8 f32 accumulate (positive summands -> <=8ulp), f64 outer.
// LDS tiles K-major with XOR swizzle: conflict-free writes, b128 reads.
__global__ __launch_bounds__(256) void k_wgemm(const float* __restrict__ A,
                                               const float* __restrict__ B,
                                               float* __restrict__ W) {
  __shared__ float As[32][68];
  __shared__ float Bs[32][68];
  const int tid = threadIdx.x;
  const int tx = tid & 15, ty = tid >> 4;      // 16x16 threads of 4x4 outputs
  const int bn = blockIdx.x, bb = blockIdx.y;
  const float* Ag = A + (size_t)bb * 64 * RR;
  const float* Bg = B + (size_t)bn * 64 * RR;
  double cd[4][4];
#pragma unroll
  for (int i = 0; i < 4; ++i)
#pragma unroll
    for (int j = 0; j < 4; ++j) cd[i][j] = 0.0;

  const int lr = tid >> 2;          // 0..63 : row within tile
  const int lc = (tid & 3) * 8;     // 0,8,16,24 : k-chunk start

  for (int k0 = 0; k0 < RR; k0 += 32) {
    __syncthreads();
    float4 a0 = *(const float4*)(Ag + (size_t)lr * RR + k0 + lc);
    float4 a1 = *(const float4*)(Ag + (size_t)lr * RR + k0 + lc + 4);
    float4 b0 = *(const float4*)(Bg + (size_t)lr * RR + k0 + lc);
    float4 b1 = *(const float4*)(Bg + (size_t)lr * RR + k0 + lc + 4);
    float av_[8] = {a0.x, a0.y, a0.z, a0.w, a1.x, a1.y, a1.z, a1.w};
    float bv_[8] = {b0.x, b0.y, b0.z, b0.w, b1.x, b1.y, b1.z, b1.w};
#pragma unroll
    for (int i = 0; i < 8; ++i) {
      int kk = lc + i;
      int sw = ((kk >> 3) & 3) << 2;          // XOR swizzle by k-octet
      As[kk][lr ^ sw] = av_[i];
      Bs[kk][lr ^ sw] = bv_[i];
    }
    __syncthreads();

    float cf[4][4];
#pragma unroll
    for (int i = 0; i < 4; ++i)
#pragma unroll
      for (int j = 0; j < 4; ++j) cf[i][j] = 0.0f;
#pragma unroll
    for (int kk = 0; kk < 32; ++kk) {
      const int sw = ((kk >> 3) & 3) << 2;
      float4 av = *(const float4*)&As[kk][(ty * 4) ^ sw];
      float4 bv = *(const float4*)&Bs[kk][(tx * 4) ^ sw];
      const float aa[4] = {av.x, av.y, av.z, av.w};
      const float bbv[4] = {bv.x, bv.y, bv.z, bv.w};
#pragma unroll
      for (int i = 0; i < 4; ++i)
#pragma unroll
        for (int j = 0; j < 4; ++j)
          cf[i][j] = fmaf(aa[i], bbv[j], cf[i][j]);
      if ((kk & 7) == 7) {
#pragma unroll
        for (int i = 0; i < 4; ++i)
#pragma unroll
          for (int j = 0; j < 4; ++j) {
            cd[i][j] += (double)cf[i][j];
            cf[i][j] = 0.0f;
          }
      }
    }
  }
#pragma unroll
  for (int i = 0; i < 4; ++i) {
    int gr = bb * 64 + ty * 4 + i;
#pragma unroll
    for (int j = 0; j < 4; ++j) {
      int gc = bn * 64 + tx * 4 + j;
      W[(size_t)gr * D_CAT + gc] = (float)cd[i][j];
    }
  }
}

// per-draw gumbel-argmax over 1024 categories
__global__ __launch_bounds__(256) void k_sample(const float* __restrict__ W, int shared_row,
                                                uint32_t key1, uint32_t key2,
                                                int* __restrict__ ixout,
                                                float* __restrict__ out, int mode_j) {
  const int b = blockIdx.x, tid = threadIdx.x;
  const float* wrow = W + (shared_row ? 0 : (size_t)b * D_CAT);
  float best = -3.4e38f; int bidx = 0x7fffffff;
  for (int k = 0; k < 4; ++k) {
    int n = tid + k * 256;
    float lg = logf(fmaxf(wrow[n], 1e-30f));
    float v = gumbel_at(key1, key2, (uint32_t)(b * D_CAT + n)) + lg;
    if (v > best || (v == best && n < bidx)) { best = v; bidx = n; }
  }
  for (int m = 32; m; m >>= 1) {
    float ov = __shfl_xor(best, m);
    int   oi = __shfl_xor(bidx, m);
    if (ov > best || (ov == best && oi < bidx)) { best = ov; bidx = oi; }
  }
  __shared__ float sv[4];
  __shared__ int   si[4];
  if ((tid & 63) == 0) { sv[tid >> 6] = best; si[tid >> 6] = bidx; }
  __syncthreads();
  if (tid == 0) {
    for (int t = 1; t < 4; ++t)
      if (sv[t] > best || (sv[t] == best && si[t] < bidx)) { best = sv[t]; bidx = si[t]; }
    ixout[b] = bidx;
    out[b * KMODES + mode_j] = (float)bidx;
  }
}

// tail[b] = Core[ix_b] (first) or Core[ix_b] @ tail[b] (in place)
__global__ __launch_bounds__(256) void k_tail(const float* __restrict__ Core,
                                              const int* __restrict__ ix,
                                              float* __restrict__ tail, int first) {
  const int b = blockIdx.x, tid = threadIdx.x;
  const int m = ix[b];
  const float* crow = Core + (size_t)m * RR;
  float* trow = tail + (size_t)b * RR;
  if (first) {
    for (int k = 0; k < 16; ++k) trow[tid + k * 256] = crow[tid + k * 256];
    return;
  }
  __shared__ float tl[RR];
  for (int k = 0; k < 16; ++k) tl[tid + k * 256] = trow[tid + k * 256];
  __syncthreads();
  float outv[16];
  for (int k = 0; k < 16; ++k) {
    int p = tid + k * 256; int a = p >> 6, bb = p & 63;
    double acc = 0.0;
    for (int c = 0; c < 64; ++c)
      acc = fma((double)crow[a * 64 + c], (double)tl[c * 64 + bb], acc);
    outv[k] = (float)acc;
  }
  for (int k = 0; k < 16; ++k) trow[tid + k * 256] = outv[k];
}

__global__ __launch_bounds__(256) void k_logp(const float* __restrict__ tail,
                                              const double* __restrict__ misc,
                                              float* __restrict__ out) {
  const int b = blockIdx.x * 256 + threadIdx.x;   // 0..2047
  double tr = 0.0;
  for (int a = 0; a < 64; ++a) tr += (double)tail[(size_t)b * RR + a * 65];
  double lp = log(fmax(tr, 1e-30)) - misc[0];
  out[NDRAWS * KMODES + b] = (float)lp;
}

// ---------------- launcher ----------------
extern "C" void kernel_launch(void* const* d_in, const int* in_sizes, int n_in,
                              void* d_out, int out_size, void* d_ws, size_t ws_size,
                              hipStream_t stream) {
  (void)in_sizes; (void)n_in;
  CorePtrs cp;
  for (int i = 0; i < KMODES; ++i) cp.p[i] = (const float*)d_in[i];
  float* outf = (float*)d_out;

  char* base = (char*)d_ws;
  const size_t o_core  = 0;                                    // f32 1024*4096
  const size_t o_w     = o_core + (size_t)D_CAT * RR * 4;      // f32 2048*1024
  const size_t o_tail  = o_w + (size_t)NDRAWS * D_CAT * 4;     // f32 2048*4096
  const size_t o_mt    = o_tail + (size_t)NDRAWS * RR * 4;     // f32 2048*4096
  const size_t o_spart = o_mt;                                 // overlap (16MB < 33.5MB)
  const size_t o_S     = o_mt + (size_t)NDRAWS * RR * 4;       // f64 8*4096
  const size_t o_heads = o_S + (size_t)KMODES * RR * 8;        // f64 7*4096
  const size_t o_ix    = o_heads + (size_t)7 * RR * 8;         // i32 2048
  const size_t o_misc  = o_ix + (size_t)NDRAWS * 4;            // f64 lognorm
  const size_t NEED    = o_misc + 256;
  if (ws_size < NEED) {
    k_sentinel<<<(out_size + 255) / 256, 256, 0, stream>>>(outf, out_size);
    return;
  }

  float*  Core  = (float*)(base + o_core);
  float*  W     = (float*)(base + o_w);
  float*  tail  = (float*)(base + o_tail);
  float*  Mt    = (float*)(base + o_mt);
  double* Spart = (double*)(base + o_spart);
  double* S     = (double*)(base + o_S);
  double* heads = (double*)(base + o_heads);
  int*    ix    = (int*)(base + o_ix);
  double* misc  = (double*)(base + o_misc);

  // keys[s] = threefry2x32((0,1), (0,s))  -- split(key(1), 8), foldlike
  uint32_t kk1[KMODES], kk2[KMODES];
  for (uint32_t s = 0; s < KMODES; ++s) tf2x32(0u, 1u, 0u, s, kk1[s], kk2[s]);

  k_spart  <<<512, 256, 0, stream>>>(cp, Spart);
  k_sreduce<<<128, 256, 0, stream>>>(Spart, S);
  k_heads  <<<1,   256, 0, stream>>>(S, heads, misc);

  for (int s = 0; s < KMODES; ++s) {
    const int j = 7 - s;
    k_softplus<<<4096, 256, 0, stream>>>(cp.p[j], Core);
    if (s == 0) {
      k_w0<<<256, 256, 0, stream>>>(Core, heads + (size_t)6 * RR, W);
    } else {
      k_mt<<<2048, 256, 0, stream>>>(tail, j > 0 ? heads + (size_t)(j - 1) * RR : nullptr,
                                     Mt, j > 0 ? 1 : 0);
      k_wgemm<<<dim3(16, 32), 256, 0, stream>>>(Mt, Core, W);
    }
    k_sample<<<NDRAWS, 256, 0, stream>>>(W, s == 0 ? 1 : 0, kk1[s], kk2[s], ix, outf, j);
    k_tail  <<<NDRAWS, 256, 0, stream>>>(Core, ix, tail, s == 0 ? 1 : 0);
  }
  k_logp<<<KMODES, 256, 0, stream>>>(tail, misc, outf);
}

// Round 4
// 4581.066 us; speedup vs baseline: 1.4522x; 1.0591x over previous
//
#include <hip/hip_runtime.h>
#include <stdint.h>
#include <math.h>

#define D_CAT  1024
#define R_TR   64
#define RR     4096      // R*R
#define NDRAWS 2048
#define KMODES 8

struct CorePtrs { const float* p[KMODES]; };

typedef __attribute__((ext_vector_type(8))) __bf16 bf16x8;
typedef __attribute__((ext_vector_type(4))) float  f32x4;

// ---------------- threefry2x32 (JAX-exact, 20 rounds) ----------------
static __host__ __device__ inline uint32_t rotl32(uint32_t x, int r) {
  return (x << r) | (x >> (32 - r));
}
static __host__ __device__ inline void tf2x32(uint32_t k1, uint32_t k2,
                                              uint32_t x0, uint32_t x1,
                                              uint32_t& o0, uint32_t& o1) {
  uint32_t ks0 = k1, ks1 = k2, ks2 = k1 ^ k2 ^ 0x1BD11BDAu;
  x0 += ks0; x1 += ks1;
  x0 += x1; x1 = rotl32(x1, 13); x1 ^= x0;
  x0 += x1; x1 = rotl32(x1, 15); x1 ^= x0;
  x0 += x1; x1 = rotl32(x1, 26); x1 ^= x0;
  x0 += x1; x1 = rotl32(x1, 6);  x1 ^= x0;
  x0 += ks1; x1 += ks2 + 1u;
  x0 += x1; x1 = rotl32(x1, 17); x1 ^= x0;
  x0 += x1; x1 = rotl32(x1, 29); x1 ^= x0;
  x0 += x1; x1 = rotl32(x1, 16); x1 ^= x0;
  x0 += x1; x1 = rotl32(x1, 24); x1 ^= x0;
  x0 += ks2; x1 += ks0 + 2u;
  x0 += x1; x1 = rotl32(x1, 13); x1 ^= x0;
  x0 += x1; x1 = rotl32(x1, 15); x1 ^= x0;
  x0 += x1; x1 = rotl32(x1, 26); x1 ^= x0;
  x0 += x1; x1 = rotl32(x1, 6);  x1 ^= x0;
  x0 += ks0; x1 += ks1 + 3u;
  x0 += x1; x1 = rotl32(x1, 17); x1 ^= x0;
  x0 += x1; x1 = rotl32(x1, 29); x1 ^= x0;
  x0 += x1; x1 = rotl32(x1, 16); x1 ^= x0;
  x0 += x1; x1 = rotl32(x1, 24); x1 ^= x0;
  x0 += ks1; x1 += ks2 + 4u;
  x0 += x1; x1 = rotl32(x1, 13); x1 ^= x0;
  x0 += x1; x1 = rotl32(x1, 15); x1 ^= x0;
  x0 += x1; x1 = rotl32(x1, 26); x1 ^= x0;
  x0 += x1; x1 = rotl32(x1, 6);  x1 ^= x0;
  x0 += ks2; x1 += ks0 + 5u;
  o0 = x0; o1 = x1;
}

// softplus exactly as jnp.logaddexp(x, 0): max(x,0) + log1p(exp(-|x|))
static __device__ inline float softplus_ref(float x) {
  return fmaxf(x, 0.0f) + log1pf(expf(-fabsf(x)));
}

static __device__ inline unsigned short f32_bf16(float f) {  // RNE
  uint32_t u = __float_as_uint(f);
  u += 0x7fffu + ((u >> 16) & 1u);
  return (unsigned short)(u >> 16);
}

// gumbel for flat element e under key (k1,k2), partitionable path
static __device__ inline float gumbel_at(uint32_t k1, uint32_t k2, uint32_t e) {
  uint32_t o0, o1;
  tf2x32(k1, k2, 0u, e, o0, o1);
  uint32_t bits = o0 ^ o1;
  float f = __uint_as_float((bits >> 9) | 0x3F800000u) - 1.0f;
  float u = (f > 0.0f) ? f : 1.17549435e-38f;   // finfo(f32).tiny
  return -logf(-logf(u));
}

// ---------------- kernels ----------------

__global__ void k_sentinel(float* out, int n) {
  int i = blockIdx.x * 256 + threadIdx.x;
  if (i < n) out[i] = -12288.0f;  // ws-too-small marker
}

// partial column sums of softplus(core_i): grid 8*64, block 256
__global__ __launch_bounds__(256) void k_spart(CorePtrs cp, double* __restrict__ Spart) {
  const int bid = blockIdx.x, tid = threadIdx.x;
  const int i = bid >> 6, c = bid & 63;
  const float* src = cp.p[i];
  double acc[16];
#pragma unroll
  for (int k = 0; k < 16; ++k) acc[k] = 0.0;
  for (int d = c * 16; d < c * 16 + 16; ++d) {
    const float* row = src + (size_t)d * RR;
#pragma unroll
    for (int k = 0; k < 16; ++k)
      acc[k] += (double)softplus_ref(row[tid + k * 256]);
  }
  double* dst = Spart + (size_t)(i * 64 + c) * RR;
#pragma unroll
  for (int k = 0; k < 16; ++k) dst[tid + k * 256] = acc[k];
}

// reduce 64 partials -> S[i][rr]: grid 128, block 256
__global__ __launch_bounds__(256) void k_sreduce(const double* __restrict__ Spart,
                                                 double* __restrict__ S) {
  const int idx = blockIdx.x * 256 + threadIdx.x;
  const int i = idx >> 12, rr = idx & 4095;
  double acc = 0.0;
  for (int c = 0; c < 64; ++c)
    acc += Spart[(size_t)(i * 64 + c) * RR + rr];
  S[(size_t)i * RR + rr] = acc;
}

// heads chain + log(trace(norm)): 1 block, 256 threads
__global__ __launch_bounds__(256) void k_heads(const double* __restrict__ S,
                                               double* __restrict__ heads,
                                               double* __restrict__ misc) {
  __shared__ double bufA[RR];
  __shared__ double bufB[RR];
  const int tid = threadIdx.x;
  double* cur = bufA; double* nxt = bufB;
  for (int k = 0; k < 16; ++k) {
    int p = tid + k * 256;
    double v = S[p];
    cur[p] = v;
    heads[p] = v;
  }
  __syncthreads();
  for (int m = 1; m <= 6; ++m) {
    for (int k = 0; k < 16; ++k) {
      int p = tid + k * 256; int a = p >> 6, bcol = p & 63;
      double acc = 0.0;
      for (int c = 0; c < 64; ++c)
        acc = fma(cur[a * 64 + c], S[(size_t)m * RR + c * 64 + bcol], acc);
      nxt[p] = acc;
    }
    __syncthreads();
    for (int k = 0; k < 16; ++k) {
      int p = tid + k * 256;
      heads[(size_t)m * RR + p] = nxt[p];
    }
    double* t = cur; cur = nxt; nxt = t;
    __syncthreads();
  }
  if (tid < 64) {
    double acc = 0.0;
    for (int c = 0; c < 64; ++c)
      acc = fma(cur[tid * 64 + c], S[(size_t)7 * RR + c * 64 + tid], acc);
    nxt[tid] = acc;
  }
  __syncthreads();
  if (tid == 0) {
    double tr = 0.0;
    for (int a = 0; a < 64; ++a) tr += nxt[a];
    misc[0] = log(tr);
  }
}

// softplus(log_core_j) -> Core f32 (+ optional bf16 hi/lo split for MFMA B)
__global__ __launch_bounds__(256) void k_softplus(const float* __restrict__ src,
                                                  float* __restrict__ dst,
                                                  ushort* __restrict__ Bh,
                                                  ushort* __restrict__ Bl,
                                                  int doSplit) {
  const size_t i4 = ((size_t)blockIdx.x * 256 + threadIdx.x) * 4;
  float4 v = *(const float4*)(src + i4);
  float4 o;
  o.x = softplus_ref(v.x); o.y = softplus_ref(v.y);
  o.z = softplus_ref(v.z); o.w = softplus_ref(v.w);
  *(float4*)(dst + i4) = o;
  if (doSplit) {
    const float ov[4] = {o.x, o.y, o.z, o.w};
    ushort h4[4], l4[4];
#pragma unroll
    for (int q = 0; q < 4; ++q) {
      ushort h = f32_bf16(ov[q]);
      float hf = __uint_as_float((uint32_t)h << 16);
      h4[q] = h;
      l4[q] = f32_bf16(ov[q] - hf);
    }
    *(ushort4*)(Bh + i4) = make_ushort4(h4[0], h4[1], h4[2], h4[3]);
    *(ushort4*)(Bl + i4) = make_ushort4(l4[0], l4[1], l4[2], l4[3]);
  }
}

// step 0 weights: w[n] = sum_q Core[n,q] * heads7[(q&63)*64 + (q>>6)]
__global__ __launch_bounds__(256) void k_w0(const float* __restrict__ Core,
                                            const double* __restrict__ head7,
                                            float* __restrict__ W) {
  const int tid = threadIdx.x;
  const int lane = tid & 63;
  const int n = blockIdx.x * 4 + (tid >> 6);
  const float* crow = Core + (size_t)n * RR;
  double acc = 0.0;
  for (int q = lane; q < RR; q += 64)
    acc = fma((double)crow[q], head7[(q & 63) * 64 + (q >> 6)], acc);
  for (int m = 32; m; m >>= 1) acc += __shfl_xor(acc, m);
  if (lane == 0) W[n] = (float)acc;
}

// Mt[b, a*64+bb] = sum_c tail[b,bb,c]*head[c,a]; emit bf16 hi/lo pair
__global__ __launch_bounds__(256) void k_mt(const float* __restrict__ tail,
                                            const double* __restrict__ head,
                                            ushort* __restrict__ Ah,
                                            ushort* __restrict__ Al, int useHead) {
  __shared__ float tl[64 * 65];
  const int b = blockIdx.x, tid = threadIdx.x;
  const float* trow = tail + (size_t)b * RR;
  for (int k = 0; k < 16; ++k) {
    int q = tid + k * 256;
    tl[(q >> 6) * 65 + (q & 63)] = trow[q];
  }
  __syncthreads();
  ushort* ah = Ah + (size_t)b * RR;
  ushort* al = Al + (size_t)b * RR;
  for (int k = 0; k < 16; ++k) {
    int p = tid + k * 256; int a = p >> 6, bb = p & 63;
    float m;
    if (useHead) {
      double acc = 0.0;
      for (int c = 0; c < 64; ++c)
        acc = fma((double)tl[bb * 65 + c], head[c * 64 + a], acc);
      m = (float)acc;
    } else {
      m = tl[bb * 65 + a];
    }
    ushort h = f32_bf16(m);
    float hf = __uint_as_float((uint32_t)h << 16);
    ah[p] = h;
    al[p] = f32_bf16(m - hf);
  }
}

// W[2048x1024] = Mt * Core^T via bf16 3-pass MFMA (hh f64-dumped, hl+lh f32).
// Block tile 64x64, BK=64, 4 waves of 32x32. LDS 16B-chunk swizzle kc^=row&7.
__global__ __launch_bounds__(256) void k_wgemm(const ushort* __restrict__ Ah,
                                               const ushort* __restrict__ Al,
                                               const ushort* __restrict__ Bh,
                                               const ushort* __restrict__ Bl,
                                               float* __restrict__ W) {
  __shared__ ushort lds[4 * 64 * 64];   // [arr(Ah,Al,Bh,Bl)][64 rows][64 k], swizzled
  const int tid = threadIdx.x;
  const int bn = blockIdx.x, bb = blockIdx.y;

  // ---- staging assignment: 8 x 16B chunks per thread ----
  const ushort* gp[8];
  int ldsoff[8];
  {
    const ushort* bases[4] = {Ah + (size_t)bb * 64 * RR, Al + (size_t)bb * 64 * RR,
                              Bh + (size_t)bn * 64 * RR, Bl + (size_t)bn * 64 * RR};
#pragma unroll
    for (int i = 0; i < 8; ++i) {
      int arr = i >> 1;
      int row = ((i & 1) << 5) + (tid >> 3);
      int kc  = tid & 7;
      gp[i] = bases[arr] + (size_t)row * RR + kc * 8;
      ldsoff[i] = arr * 4096 + (row * 8 + (kc ^ (row & 7))) * 8;
    }
  }

  // ---- wave/lane geometry ----
  const int w = tid >> 6, l = tid & 63;
  const int wm = (w >> 1) * 32, wn = (w & 1) * 32;
  const int lrow = l & 15;          // row-in-16 for A/B frags, col for D
  const int kg   = l >> 4;          // k-group 0..3

  f32x4 acc_hh[2][2], acc_hl[2][2], acc_lh[2][2];
  double hhd[2][2][4];
#pragma unroll
  for (int mt = 0; mt < 2; ++mt)
#pragma unroll
    for (int nt = 0; nt < 2; ++nt) {
      acc_hh[mt][nt] = (f32x4)0.0f; acc_hl[mt][nt] = (f32x4)0.0f;
      acc_lh[mt][nt] = (f32x4)0.0f;
#pragma unroll
      for (int q = 0; q < 4; ++q) hhd[mt][nt][q] = 0.0;
    }

  // precomputed LDS read offsets (ushort units)
  int roffA[2][2], roffB[2][2];   // [mt|nt][kt]
#pragma unroll
  for (int mt = 0; mt < 2; ++mt)
#pragma unroll
    for (int kt = 0; kt < 2; ++kt) {
      int rowA = wm + mt * 16 + lrow;
      int kcA  = kt * 4 + kg;
      roffA[mt][kt] = (rowA * 8 + ((kcA ^ (rowA & 7)))) * 8;
      int rowB = wn + mt * 16 + lrow;
      roffB[mt][kt] = (rowB * 8 + ((kcA ^ (rowB & 7)))) * 8;
    }

  uint4 st[8];
#pragma unroll
  for (int i = 0; i < 8; ++i) st[i] = *(const uint4*)(gp[i]);

  for (int t = 0; t < 64; ++t) {
#pragma unroll
    for (int i = 0; i < 8; ++i) *(uint4*)&lds[ldsoff[i]] = st[i];
    __syncthreads();
    if (t < 63) {
      const int k0 = (t + 1) * 64;
#pragma unroll
      for (int i = 0; i < 8; ++i) st[i] = *(const uint4*)(gp[i] + k0);
    }
#pragma unroll
    for (int kt = 0; kt < 2; ++kt) {
      bf16x8 ah[2], al[2], bh[2], bl[2];
#pragma unroll
      for (int mt = 0; mt < 2; ++mt) {
        ah[mt] = *(const bf16x8*)&lds[0 * 4096 + roffA[mt][kt]];
        al[mt] = *(const bf16x8*)&lds[1 * 4096 + roffA[mt][kt]];
      }
#pragma unroll
      for (int nt = 0; nt < 2; ++nt) {
        bh[nt] = *(const bf16x8*)&lds[2 * 4096 + roffB[nt][kt]];
        bl[nt] = *(const bf16x8*)&lds[3 * 4096 + roffB[nt][kt]];
      }
#pragma unroll
      for (int mt = 0; mt < 2; ++mt)
#pragma unroll
        for (int nt = 0; nt < 2; ++nt) {
          acc_hh[mt][nt] = __builtin_amdgcn_mfma_f32_16x16x32_bf16(ah[mt], bh[nt], acc_hh[mt][nt], 0, 0, 0);
          acc_hl[mt][nt] = __builtin_amdgcn_mfma_f32_16x16x32_bf16(ah[mt], bl[nt], acc_hl[mt][nt], 0, 0, 0);
          acc_lh[mt][nt] = __builtin_amdgcn_mfma_f32_16x16x32_bf16(al[mt], bh[nt], acc_lh[mt][nt], 0, 0, 0);
        }
    }
    if ((t & 15) == 15) {   // f64 dump of hh every 1024 k
#pragma unroll
      for (int mt = 0; mt < 2; ++mt)
#pragma unroll
        for (int nt = 0; nt < 2; ++nt) {
#pragma unroll
          for (int q = 0; q < 4; ++q) {
            hhd[mt][nt][q] += (double)acc_hh[mt][nt][q];
          }
          acc_hh[mt][nt] = (f32x4)0.0f;
        }
    }
    __syncthreads();
  }

  // epilogue: D mapping col=lane&15, row=(lane>>4)*4+reg  [m89-verified]
#pragma unroll
  for (int mt = 0; mt < 2; ++mt)
#pragma unroll
    for (int nt = 0; nt < 2; ++nt)
#pragma unroll
      for (int q = 0; q < 4; ++q) {
        int gr = bb * 64 + wm + mt * 16 + kg * 4 + q;
        int gc = bn * 64 + wn + nt * 16 + lrow;
        double v = hhd[mt][nt][q] + (double)acc_hl[mt][nt][q] + (double)acc_lh[mt][nt][q];
        W[(size_t)gr * D_CAT + gc] = (float)v;
      }
}

// per-draw gumbel-argmax over 1024 categories
__global__ __launch_bounds__(256) void k_sample(const float* __restrict__ W, int shared_row,
                                                uint32_t key1, uint32_t key2,
                                                int* __restrict__ ixout,
                                                float* __restrict__ out, int mode_j) {
  const int b = blockIdx.x, tid = threadIdx.x;
  const float* wrow = W + (shared_row ? 0 : (size_t)b * D_CAT);
  float best = -3.4e38f; int bidx = 0x7fffffff;
  for (int k = 0; k < 4; ++k) {
    int n = tid + k * 256;
    float lg = logf(fmaxf(wrow[n], 1e-30f));
    float v = gumbel_at(key1, key2, (uint32_t)(b * D_CAT + n)) + lg;
    if (v > best || (v == best && n < bidx)) { best = v; bidx = n; }
  }
  for (int m = 32; m; m >>= 1) {
    float ov = __shfl_xor(best, m);
    int   oi = __shfl_xor(bidx, m);
    if (ov > best || (ov == best && oi < bidx)) { best = ov; bidx = oi; }
  }
  __shared__ float sv[4];
  __shared__ int   si[4];
  if ((tid & 63) == 0) { sv[tid >> 6] = best; si[tid >> 6] = bidx; }
  __syncthreads();
  if (tid == 0) {
    for (int t = 1; t < 4; ++t)
      if (sv[t] > best || (sv[t] == best && si[t] < bidx)) { best = sv[t]; bidx = si[t]; }
    ixout[b] = bidx;
    out[b * KMODES + mode_j] = (float)bidx;
  }
}

// tail[b] = Core[ix_b] (first) or Core[ix_b] @ tail[b] (in place)
__global__ __launch_bounds__(256) void k_tail(const float* __restrict__ Core,
                                              const int* __restrict__ ix,
                                              float* __restrict__ tail, int first) {
  const int b = blockIdx.x, tid = threadIdx.x;
  const int m = ix[b];
  const float* crow = Core + (size_t)m * RR;
  float* trow = tail + (size_t)b * RR;
  if (first) {
    for (int k = 0; k < 16; ++k) trow[tid + k * 256] = crow[tid + k * 256];
    return;
  }
  __shared__ float tl[RR];
  for (int k = 0; k < 16; ++k) tl[tid + k * 256] = trow[tid + k * 256];
  __syncthreads();
  float outv[16];
  for (int k = 0; k < 16; ++k) {
    int p = tid + k * 256; int a = p >> 6, bb = p & 63;
    double acc = 0.0;
    for (int c = 0; c < 64; ++c)
      acc = fma((double)crow[a * 64 + c], (double)tl[c * 64 + bb], acc);
    outv[k] = (float)acc;
  }
  for (int k = 0; k < 16; ++k) trow[tid + k * 256] = outv[k];
}

__global__ __launch_bounds__(256) void k_logp(const float* __restrict__ tail,
                                              const double* __restrict__ misc,
                                              float* __restrict__ out) {
  const int b = blockIdx.x * 256 + threadIdx.x;
  double tr = 0.0;
  for (int a = 0; a < 64; ++a) tr += (double)tail[(size_t)b * RR + a * 65];
  double lp = log(fmax(tr, 1e-30)) - misc[0];
  out[NDRAWS * KMODES + b] = (float)lp;
}

// ---------------- launcher ----------------
extern "C" void kernel_launch(void* const* d_in, const int* in_sizes, int n_in,
                              void* d_out, int out_size, void* d_ws, size_t ws_size,
                              hipStream_t stream) {
  (void)in_sizes; (void)n_in;
  CorePtrs cp;
  for (int i = 0; i < KMODES; ++i) cp.p[i] = (const float*)d_in[i];
  float* outf = (float*)d_out;

  char* base = (char*)d_ws;
  const size_t o_core  = 0;                                    // f32 1024*4096
  const size_t o_w     = o_core + (size_t)D_CAT * RR * 4;      // f32 2048*1024
  const size_t o_tail  = o_w + (size_t)NDRAWS * D_CAT * 4;     // f32 2048*4096
  const size_t o_ahl   = o_tail + (size_t)NDRAWS * RR * 4;     // u16 Ah+Al (2x 2048*4096)
  const size_t o_spart = o_ahl;                                // f64 overlap (prologue only)
  const size_t o_S     = o_ahl + (size_t)NDRAWS * RR * 4;      // f64 8*4096
  const size_t o_heads = o_S + (size_t)KMODES * RR * 8;        // f64 7*4096
  const size_t o_ix    = o_heads + (size_t)7 * RR * 8;         // i32 2048
  const size_t o_misc  = o_ix + (size_t)NDRAWS * 4;            // f64 lognorm
  const size_t o_bh    = o_misc + 256;                         // u16 1024*4096
  const size_t o_bl    = o_bh + (size_t)D_CAT * RR * 2;        // u16 1024*4096
  const size_t NEED    = o_bl + (size_t)D_CAT * RR * 2;
  if (ws_size < NEED) {
    k_sentinel<<<(out_size + 255) / 256, 256, 0, stream>>>(outf, out_size);
    return;
  }

  float*  Core  = (float*)(base + o_core);
  float*  W     = (float*)(base + o_w);
  float*  tail  = (float*)(base + o_tail);
  ushort* Ah    = (ushort*)(base + o_ahl);
  ushort* Al    = Ah + (size_t)NDRAWS * RR;
  double* Spart = (double*)(base + o_spart);
  double* S     = (double*)(base + o_S);
  double* heads = (double*)(base + o_heads);
  int*    ix    = (int*)(base + o_ix);
  double* misc  = (double*)(base + o_misc);
  ushort* Bh    = (ushort*)(base + o_bh);
  ushort* Bl    = (ushort*)(base + o_bl);

  // keys[s] = threefry2x32((0,1), (0,s))  -- split(key(1), 8), foldlike
  uint32_t kk1[KMODES], kk2[KMODES];
  for (uint32_t s = 0; s < KMODES; ++s) tf2x32(0u, 1u, 0u, s, kk1[s], kk2[s]);

  k_spart  <<<512, 256, 0, stream>>>(cp, Spart);
  k_sreduce<<<128, 256, 0, stream>>>(Spart, S);
  k_heads  <<<1,   256, 0, stream>>>(S, heads, misc);

  for (int s = 0; s < KMODES; ++s) {
    const int j = 7 - s;
    k_softplus<<<4096, 256, 0, stream>>>(cp.p[j], Core, Bh, Bl, s == 0 ? 0 : 1);
    if (s == 0) {
      k_w0<<<256, 256, 0, stream>>>(Core, heads + (size_t)6 * RR, W);
    } else {
      k_mt<<<2048, 256, 0, stream>>>(tail, j > 0 ? heads + (size_t)(j - 1) * RR : nullptr,
                                     Ah, Al, j > 0 ? 1 : 0);
      k_wgemm<<<dim3(16, 32), 256, 0, stream>>>(Ah, Al, Bh, Bl, W);
    }
    k_sample<<<NDRAWS, 256, 0, stream>>>(W, s == 0 ? 1 : 0, kk1[s], kk2[s], ix, outf, j);
    k_tail  <<<NDRAWS, 256, 0, stream>>>(Core, ix, tail, s == 0 ? 1 : 0);
  }
  k_logp<<<KMODES, 256, 0, stream>>>(tail, misc, outf);
}